// Round 10
// baseline (138.784 us; speedup 1.0000x reference)
//
#include <hip/hip_runtime.h>

// GNN surrogate — r27: remove s_setprio brackets (single variable vs r26).
// r26 post-mortem: SB removal neutral (48.4us) -> compiler reproduces manual
// schedule; the REMAINING fence is the setprio(1)/(0) pair (since r21, never
// ablated solo). It pins each GSTEP into an indivisible pure-MFMA cluster,
// so pkc/cat VALU bursts can't interleave into the next cluster. Both
// resident waves run in lockstep -> SIMD alternates all-MFMA / all-VALU
// phases: pipes pay SUM (21.7 MFMA + 16 VALU + stalls ~= 48us) not MAX.
// m190 also measured setprio NEGATIVE on lockstep GEMM-like structures.
// r27: identical to r26 minus the brackets; scheduler free to homogenize.
// NEVER use __launch_bounds__(256,3): 168-reg budget force-splits 84/84 and
// spills the 128-VGPR half8 state (r15/r16/r19/r25 — four failures).
// WRITE_SIZE<=128KB is the spill tripwire for scheduler over-hoisting.

typedef _Float16 f16;
typedef __attribute__((ext_vector_type(8))) _Float16 half8;
typedef __attribute__((ext_vector_type(4))) _Float16 half4;
typedef __attribute__((ext_vector_type(2))) __fp16 fp16x2;
typedef __attribute__((ext_vector_type(4))) float f32x4;

namespace {
constexpr int N = 128, H = 32;
constexpr int WS_ADJB = 0;       // f16 [8gi][4c][64lane][8] K=32 adj B-tiles (32768 B)
constexpr int WS_W0B  = 32768;   // f16 [2t][64lane][4]  W1eff K=16 B-tiles   (1024 B)
constexpr int WS_MB   = 33792;   // f16 [2l][2t][64lane][8] Meff K=32 B-tiles (4096 B)
constexpr int WS_BIAS = 37888;   // f32 [3][32]
constexpr int WS_V    = 38400;   // f32 [128]
constexpr int WS_U    = 38912;   // f32 [32]
constexpr int WS_C    = 39040;   // f32 [1]
}

static __device__ __forceinline__ half4 pk4(float a, float b, float c, float d) {
  union { half4 v; fp16x2 h[2]; } u;
  u.h[0] = __builtin_amdgcn_cvt_pkrtz(a, b);
  u.h[1] = __builtin_amdgcn_cvt_pkrtz(c, d);
  return u.v;
}
static __device__ __forceinline__ half4 relupk(f32x4 c) {
  const half4 z = {};
  return __builtin_elementwise_max(pk4(c[0], c[1], c[2], c[3]), z);
}
static __device__ __forceinline__ half4 pkc(f32x4 c) {
  return pk4(c[0], c[1], c[2], c[3]);
}
static __device__ __forceinline__ half8 cat(half4 lo, half4 hi) {
  return __builtin_shufflevector(lo, hi, 0, 1, 2, 3, 4, 5, 6, 7);
}

#define MF(A, B, C)   __builtin_amdgcn_mfma_f32_16x16x16f16((A), (B), (C), 0, 0, 0)
#define MF32(A, B, C) __builtin_amdgcn_mfma_f32_16x16x32_f16((A), (B), (C), 0, 0, 0)

// ---- prep: 13 independent blocks, redundant compute, no cross-block deps ----
__global__ void prep(const float* __restrict__ adj,
                     const float* __restrict__ W_lift,
                     const float* __restrict__ b_lift,
                     const float* __restrict__ W1,
                     const float* __restrict__ b1,
                     const float* __restrict__ W2,
                     const float* __restrict__ b2,
                     const float* __restrict__ W_ro,
                     const float* __restrict__ b_ro,
                     char* __restrict__ ws) {
  const int tid = threadIdx.x;
  const int bx  = blockIdx.x;
  f16* adjb  = (f16*)(ws + WS_ADJB);
  f16* w0b   = (f16*)(ws + WS_W0B);
  f16* mb    = (f16*)(ws + WS_MB);
  float* bia = (float*)(ws + WS_BIAS);
  float* v   = (float*)(ws + WS_V);
  float* u   = (float*)(ws + WS_U);
  float* cp  = (float*)(ws + WS_C);

  if (bx >= 1 && bx <= 8) {
    // K=32 adjacency B-tiles, one gi per block (verified r18).
    const int e = (bx - 1) * 256 + tid;
    const int gi = e >> 8, c = (e >> 6) & 3, lane = e & 63;
    const int lr = lane & 15, q = lane >> 4;
    const float* src = adj + (gi * 16 + lr) * N + c * 32;
    f16* dst = adjb + e * 8;
#pragma unroll
    for (int j = 0; j < 8; ++j) {
      const int col = (j < 4) ? (4 * q + j) : (12 + 4 * q + j);  // lambda
      dst[j] = (f16)src[col];
    }
    return;
  }

  if (bx == 0) {
    // adj column sums -> v; cp = c2r * sum(v) + b_ro.
    __shared__ float vpart[2][N];
    const int c = tid & 127, h = tid >> 7;
    float s = 0.f;
#pragma unroll 8
    for (int i = h * 64; i < h * 64 + 64; ++i) s += adj[i * N + c];
    vpart[h][c] = s;
    __syncthreads();
    if (tid < N) v[tid] = (vpart[0][tid] + vpart[1][tid]) * (1.0f / N);
    if (tid < 64) {
      float sv = (vpart[0][tid] + vpart[1][tid] +
                  vpart[0][64 + tid] + vpart[1][64 + tid]) * (1.0f / N);
      float cc = (tid < 32) ? b2[2 * H + tid] * W_ro[tid] : 0.f;
#pragma unroll
      for (int off = 32; off > 0; off >>= 1) {
        sv += __shfl_down(sv, off, 64);
        cc += __shfl_down(cc, off, 64);
      }
      if (tid == 0) cp[0] = cc * sv + b_ro[0];
    }
    return;
  }

  if (bx == 9) {
    // tmp[0] = W_lift @ W1[0] (rows k<3 live, rest 0) -> w0b pack.
    __shared__ float t0[3][H];
    if (tid < 96) {
      const int k = tid >> 5, fo = tid & 31;
      float val = 0.f;
      for (int c = 0; c < H; ++c) val += W_lift[k * H + c] * W1[c * H + fo];
      t0[k][fo] = val;
    }
    __syncthreads();
    for (int e = tid; e < 512; e += 256) {
      const int t = e >> 8, lane = (e >> 2) & 63, j = e & 3;
      const int lr = lane & 15, q = lane >> 4;
      const int k = q * 4 + j;
      w0b[e] = (f16)((k < 3) ? t0[k][t * 16 + lr] : 0.f);
    }
    return;
  }

  if (bx == 10 || bx == 11) {
    // tmp[l] = W2[l-1] @ W1[l] -> mb[l-1] pack (lambda-permuted K=32 rows).
    const int l = bx - 9;  // 1 or 2
    __shared__ float tl[H][H];
    const float* w2l = W2 + (l - 1) * H * H;
    const float* w1n = W1 + l * H * H;
    for (int idx = tid; idx < H * H; idx += 256) {
      const int k = idx >> 5, fo = idx & 31;
      float val = 0.f;
      for (int c = 0; c < H; ++c) val += w2l[k * H + c] * w1n[c * H + fo];
      tl[k][fo] = val;
    }
    __syncthreads();
    for (int e = tid; e < 1024; e += 256) {
      const int t = e >> 9, lane = (e >> 3) & 63, j = e & 7;
      const int lr = lane & 15, q = lane >> 4;
      const int k = (j < 4) ? (4 * q + j) : (12 + 4 * q + j);  // lambda
      mb[(l - 1) * 1024 + e] = (f16)tl[k][t * 16 + lr];
    }
    return;
  }

  // bx == 12: folded biases (3 x 32 dots) + u (32 dots), one dot per thread.
  if (tid < 96) {
    const int p = tid >> 5, fo = tid & 31;
    if (p == 0) {
      float s = b1[fo];
      for (int c = 0; c < H; ++c) s += b_lift[c] * W1[c * H + fo];
      bia[fo] = s;
    } else if (p == 1) {
      float s = b1[H + fo];
      for (int c = 0; c < H; ++c) s += b2[c] * W1[H * H + c * H + fo];
      bia[H + fo] = s;
    } else {
      float s = b1[2 * H + fo];
      for (int c = 0; c < H; ++c) s += b2[H + c] * W1[2 * H * H + c * H + fo];
      bia[2 * H + fo] = s;
    }
  } else if (tid < 128) {
    const int f = tid & 31;
    float su = 0.f;
    for (int c = 0; c < H; ++c) su += W2[2 * H * H + f * H + c] * W_ro[c];
    u[f] = su;
  }
}

__global__ __launch_bounds__(256, 2)
void gnn_mfma(const float* __restrict__ x,
              const char* __restrict__ ws,
              float* __restrict__ out) {
  const f16* adjb  = (const f16*)(ws + WS_ADJB);
  const f16* w0b   = (const f16*)(ws + WS_W0B);
  const f16* mb    = (const f16*)(ws + WS_MB);
  const float* bia = (const float*)(ws + WS_BIAS);
  const float* v   = (const float*)(ws + WS_V);
  const float* u   = (const float*)(ws + WS_U);
  const float* cp  = (const float*)(ws + WS_C);

  const int tid  = threadIdx.x;
  const int wave = tid >> 6;
  const int lane = tid & 63;
  const int lrow = lane & 15;
  const int quad = lane >> 4;
  const int b0   = blockIdx.x * 8 + wave * 2;
  const int b1   = b0 + 1;

  const f32x4 zero = {0.f, 0.f, 0.f, 0.f};

  // Persistent 2-batch state (32 half8 = 128 VGPR across the ping-pong).
  half8 caA0, caA1, caA2, caA3, cbA0, cbA1, cbA2, cbA3;
  half8 caB0, caB1, caB2, caB3, cbB0, cbB1, cbB2, cbB3;
  half8 pfA0, pfA1, pfA2, pfA3, pfA4, pfA5, pfA6, pfA7;
  half8 pfB0, pfB1, pfB2, pfB3, pfB4, pfB5, pfB6, pfB7;
  // adjb register double-buffer + prefetched m-tiles.
  half8 bp0, bp1, bp2, bp3, bq0, bq1, bq2, bq3;
  half8 mw0, mw1;

#define GLOAD(gi, B0, B1, B2, B3)                                            \
  {                                                                          \
    const f16* ab = adjb + ((gi) * 256 + lane) * 8;                          \
    B0 = *(const half8*)(ab + 0 * 512);                                      \
    B1 = *(const half8*)(ab + 1 * 512);                                      \
    B2 = *(const half8*)(ab + 2 * 512);                                      \
    B3 = *(const half8*)(ab + 3 * 512);                                      \
  }
#define GMFMA(B0, B1, B2, B3, PFA, PFB)                                      \
  {                                                                          \
    f32x4 aA0 = zero, aA1 = zero, aB0 = zero, aB1 = zero;                    \
    aA0 = MF32(caA0, B0, aA0); aA1 = MF32(cbA0, B0, aA1);                    \
    aB0 = MF32(caB0, B0, aB0); aB1 = MF32(cbB0, B0, aB1);                    \
    aA0 = MF32(caA1, B1, aA0); aA1 = MF32(cbA1, B1, aA1);                    \
    aB0 = MF32(caB1, B1, aB0); aB1 = MF32(cbB1, B1, aB1);                    \
    aA0 = MF32(caA2, B2, aA0); aA1 = MF32(cbA2, B2, aA1);                    \
    aB0 = MF32(caB2, B2, aB0); aB1 = MF32(cbB2, B2, aB1);                    \
    aA0 = MF32(caA3, B3, aA0); aA1 = MF32(cbA3, B3, aA1);                    \
    aB0 = MF32(caB3, B3, aB0); aB1 = MF32(cbB3, B3, aB1);                    \
    PFA = cat(pkc(aA0), pkc(aA1));                                           \
    PFB = cat(pkc(aB0), pkc(aB1));                                           \
  }

  // ---- prologue: hoist scalars + first G-tiles (latency hidden by L0) ----
  const float cpv = cp[0];
  const float u0 = u[lrow], u1 = u[16 + lrow];
  const float bL1a = bia[H + lrow], bL1b = bia[H + 16 + lrow];
  const float bL2a = bia[2 * H + lrow], bL2b = bia[2 * H + 16 + lrow];
  GLOAD(0, bp0, bp1, bp2, bp3)
  GLOAD(1, bq0, bq1, bq2, bq3)

  // ---- L0: T0 = relu(x·W1eff + b0), K=16 MFMA, both batches ----
  {
    const half4 w0 = *(const half4*)(w0b + (0 * 64 + lane) * 4);
    const half4 w1 = *(const half4*)(w0b + (1 * 64 + lane) * 4);
    const float bb0 = bia[lrow], bb1 = bia[16 + lrow];
    const f32x4 bi0 = {bb0, bb0, bb0, bb0};
    const f32x4 bi1 = {bb1, bb1, bb1, bb1};
#define L0PAIR(g, CAA, CBA, CAB, CBB)                                        \
    {                                                                        \
      half4 xA0 = {}, xA1 = {}, xB0 = {}, xB1 = {};                          \
      if (quad == 0) {                                                       \
        const float* ra0 = x + ((size_t)b0 * N + (g) * 16 + lrow) * 3;       \
        const float* ra1 = x + ((size_t)b0 * N + ((g) + 1) * 16 + lrow) * 3; \
        const float* rb0 = x + ((size_t)b1 * N + (g) * 16 + lrow) * 3;       \
        const float* rb1 = x + ((size_t)b1 * N + ((g) + 1) * 16 + lrow) * 3; \
        xA0 = pk4(ra0[0], ra0[1], ra0[2], 0.f);                              \
        xA1 = pk4(ra1[0], ra1[1], ra1[2], 0.f);                              \
        xB0 = pk4(rb0[0], rb0[1], rb0[2], 0.f);                              \
        xB1 = pk4(rb1[0], rb1[1], rb1[2], 0.f);                              \
      }                                                                      \
      CAA = cat(relupk(MF(xA0, w0, bi0)), relupk(MF(xA1, w0, bi0)));         \
      CBA = cat(relupk(MF(xA0, w1, bi1)), relupk(MF(xA1, w1, bi1)));         \
      CAB = cat(relupk(MF(xB0, w0, bi0)), relupk(MF(xB1, w0, bi0)));         \
      CBB = cat(relupk(MF(xB0, w1, bi1)), relupk(MF(xB1, w1, bi1)));         \
    }
    L0PAIR(0, caA0, cbA0, caB0, cbB0) L0PAIR(2, caA1, cbA1, caB1, cbB1)
    L0PAIR(4, caA2, cbA2, caB2, cbB2) L0PAIR(6, caA3, cbA3, caB3, cbB3)
#undef L0PAIR
  }

  // ---- G0: each region issues GSTEP g+2's loads under g's MFMAs ----
  GMFMA(bp0, bp1, bp2, bp3, pfA0, pfB0) GLOAD(2, bp0, bp1, bp2, bp3)
  GMFMA(bq0, bq1, bq2, bq3, pfA1, pfB1) GLOAD(3, bq0, bq1, bq2, bq3)
  GMFMA(bp0, bp1, bp2, bp3, pfA2, pfB2) GLOAD(4, bp0, bp1, bp2, bp3)
  GMFMA(bq0, bq1, bq2, bq3, pfA3, pfB3) GLOAD(5, bq0, bq1, bq2, bq3)
  GMFMA(bp0, bp1, bp2, bp3, pfA4, pfB4) GLOAD(6, bp0, bp1, bp2, bp3)
  GMFMA(bq0, bq1, bq2, bq3, pfA5, pfB5) GLOAD(7, bq0, bq1, bq2, bq3)
  GMFMA(bp0, bp1, bp2, bp3, pfA6, pfB6)
  { // prefetch L1 m-tiles
    mw0 = *(const half8*)(mb + (0 * 64 + lane) * 8);
    mw1 = *(const half8*)(mb + (1 * 64 + lane) * 8);
  }
  GMFMA(bq0, bq1, bq2, bq3, pfA7, pfB7)
  GLOAD(0, bp0, bp1, bp2, bp3) GLOAD(1, bq0, bq1, bq2, bq3)  // G1 tiles

  // ---- L1: consumes pf pairs, emits G-friendly cats; both batches ----
  {
    const f32x4 bi0 = {bL1a, bL1a, bL1a, bL1a};
    const f32x4 bi1 = {bL1b, bL1b, bL1b, bL1b};
#define L1PAIR(PF0, PF1, CA, CB)                                             \
    {                                                                        \
      f32x4 c0a = MF32(PF0, mw0, bi0);                                       \
      f32x4 c1a = MF32(PF0, mw1, bi1);                                       \
      f32x4 c0b = MF32(PF1, mw0, bi0);                                       \
      f32x4 c1b = MF32(PF1, mw1, bi1);                                       \
      CA = cat(relupk(c0a), relupk(c0b));                                    \
      CB = cat(relupk(c1a), relupk(c1b));                                    \
    }
    L1PAIR(pfA0, pfA1, caA0, cbA0) L1PAIR(pfB0, pfB1, caB0, cbB0)
    L1PAIR(pfA2, pfA3, caA1, cbA1) L1PAIR(pfB2, pfB3, caB1, cbB1)
    L1PAIR(pfA4, pfA5, caA2, cbA2) L1PAIR(pfB4, pfB5, caB2, cbB2)
    L1PAIR(pfA6, pfA7, caA3, cbA3) L1PAIR(pfB6, pfB7, caB3, cbB3)
#undef L1PAIR
  }

  // ---- G1: same pipeline; region6 prefetches L2 m-tiles ----
  GMFMA(bp0, bp1, bp2, bp3, pfA0, pfB0) GLOAD(2, bp0, bp1, bp2, bp3)
  GMFMA(bq0, bq1, bq2, bq3, pfA1, pfB1) GLOAD(3, bq0, bq1, bq2, bq3)
  GMFMA(bp0, bp1, bp2, bp3, pfA2, pfB2) GLOAD(4, bp0, bp1, bp2, bp3)
  GMFMA(bq0, bq1, bq2, bq3, pfA3, pfB3) GLOAD(5, bq0, bq1, bq2, bq3)
  GMFMA(bp0, bp1, bp2, bp3, pfA4, pfB4) GLOAD(6, bp0, bp1, bp2, bp3)
  GMFMA(bq0, bq1, bq2, bq3, pfA5, pfB5) GLOAD(7, bq0, bq1, bq2, bq3)
  GMFMA(bp0, bp1, bp2, bp3, pfA6, pfB6)
  { // prefetch L2 m-tiles
    mw0 = *(const half8*)(mb + 1024 + (0 * 64 + lane) * 8);
    mw1 = *(const half8*)(mb + 1024 + (1 * 64 + lane) * 8);
  }
  GMFMA(bq0, bq1, bq2, bq3, pfA7, pfB7)

#undef GMFMA
#undef GLOAD

  // ---- L2 + folded readout, both batches ----
  {
    const f32x4 bi0 = {bL2a, bL2a, bL2a, bL2a};
    const f32x4 bi1 = {bL2b, bL2b, bL2b, bL2b};
    float pA = 0.f, pB = 0.f;
#define L2G(g, PF, ACC)                                                      \
    {                                                                        \
      f32x4 c0 = MF32(PF, mw0, bi0);                                         \
      f32x4 c1 = MF32(PF, mw1, bi1);                                         \
      const float4 vv = *(const float4*)(v + (g) * 16 + quad * 4);           \
      ACC += (fmaxf(c0[0], 0.f) * vv.x + fmaxf(c0[1], 0.f) * vv.y +          \
              fmaxf(c0[2], 0.f) * vv.z + fmaxf(c0[3], 0.f) * vv.w) * u0 +    \
             (fmaxf(c1[0], 0.f) * vv.x + fmaxf(c1[1], 0.f) * vv.y +          \
              fmaxf(c1[2], 0.f) * vv.z + fmaxf(c1[3], 0.f) * vv.w) * u1;     \
    }
    L2G(0, pfA0, pA) L2G(0, pfB0, pB) L2G(1, pfA1, pA) L2G(1, pfB1, pB)
    L2G(2, pfA2, pA) L2G(2, pfB2, pB) L2G(3, pfA3, pA) L2G(3, pfB3, pB)
    L2G(4, pfA4, pA) L2G(4, pfB4, pB) L2G(5, pfA5, pA) L2G(5, pfB5, pB)
    L2G(6, pfA6, pA) L2G(6, pfB6, pB) L2G(7, pfA7, pA) L2G(7, pfB7, pB)
#undef L2G
#pragma unroll
    for (int off = 32; off > 0; off >>= 1) {
      pA += __shfl_down(pA, off, 64);
      pB += __shfl_down(pB, off, 64);
    }
    if (lane == 0) {
      out[b0] = pA + cpv;
      out[b1] = pB + cpv;
    }
  }
}

extern "C" void kernel_launch(void* const* d_in, const int* in_sizes, int n_in,
                              void* d_out, int out_size, void* d_ws, size_t ws_size,
                              hipStream_t stream) {
  const float* x      = (const float*)d_in[0];
  const float* adj    = (const float*)d_in[1];
  const float* W_lift = (const float*)d_in[2];
  const float* b_lift = (const float*)d_in[3];
  const float* W1     = (const float*)d_in[4];
  const float* b1     = (const float*)d_in[5];
  const float* W2     = (const float*)d_in[6];
  const float* b2     = (const float*)d_in[7];
  const float* W_ro   = (const float*)d_in[8];
  const float* b_ro   = (const float*)d_in[9];
  char* ws = (char*)d_ws;
  float* o = (float*)d_out;

  const int B = in_sizes[0] / (N * 3);   // 16384
  hipLaunchKernelGGL(prep, dim3(13), dim3(256), 0, stream,
                     adj, W_lift, b_lift, W1, b1, W2, b2, W_ro, b_ro, ws);
  hipLaunchKernelGGL(gnn_mfma, dim3(B / 8), dim3(256), 0, stream,
                     x, (const char*)ws, o);
}

// Round 12
// 120.014 us; speedup vs baseline: 1.1564x; 1.1564x over previous
//
#include <hip/hip_runtime.h>

// GNN surrogate — r29: r28 (deferred-conversion ping-pong) with the macro
// arg-counting bug fixed (XS/YS expanded AFTER arg counting -> too-few-args;
// now all 14 GREG args are spelled explicitly).
// Theory unchanged from r28: acc sets X/Y ping-pong; region g+1's setprio
// bracket contains BOTH its 16 MFMAs AND region g's 8 conversion VALU ops
// (independent -> scheduler interleaves them under the ~19cyc MFMA shadow).
// Bracket boundaries still block r27's global over-hoisting. +16 AGPR.
// NEVER use __launch_bounds__(256,3): 168-reg budget force-splits 84/84 and
// spills the 128-VGPR half8 state (r15/r16/r19/r25 — four failures).
// NEVER remove the setprio brackets wholesale (r27: spills, 77us).
// WRITE_SIZE<=128KB is the spill tripwire.

typedef _Float16 f16;
typedef __attribute__((ext_vector_type(8))) _Float16 half8;
typedef __attribute__((ext_vector_type(4))) _Float16 half4;
typedef __attribute__((ext_vector_type(2))) __fp16 fp16x2;
typedef __attribute__((ext_vector_type(4))) float f32x4;

namespace {
constexpr int N = 128, H = 32;
constexpr int WS_ADJB = 0;       // f16 [8gi][4c][64lane][8] K=32 adj B-tiles (32768 B)
constexpr int WS_W0B  = 32768;   // f16 [2t][64lane][4]  W1eff K=16 B-tiles   (1024 B)
constexpr int WS_MB   = 33792;   // f16 [2l][2t][64lane][8] Meff K=32 B-tiles (4096 B)
constexpr int WS_BIAS = 37888;   // f32 [3][32]
constexpr int WS_V    = 38400;   // f32 [128]
constexpr int WS_U    = 38912;   // f32 [32]
constexpr int WS_C    = 39040;   // f32 [1]
}

static __device__ __forceinline__ half4 pk4(float a, float b, float c, float d) {
  union { half4 v; fp16x2 h[2]; } u;
  u.h[0] = __builtin_amdgcn_cvt_pkrtz(a, b);
  u.h[1] = __builtin_amdgcn_cvt_pkrtz(c, d);
  return u.v;
}
static __device__ __forceinline__ half4 relupk(f32x4 c) {
  const half4 z = {};
  return __builtin_elementwise_max(pk4(c[0], c[1], c[2], c[3]), z);
}
static __device__ __forceinline__ half4 pkc(f32x4 c) {
  return pk4(c[0], c[1], c[2], c[3]);
}
static __device__ __forceinline__ half8 cat(half4 lo, half4 hi) {
  return __builtin_shufflevector(lo, hi, 0, 1, 2, 3, 4, 5, 6, 7);
}

#define MF(A, B, C)   __builtin_amdgcn_mfma_f32_16x16x16f16((A), (B), (C), 0, 0, 0)
#define MF32(A, B, C) __builtin_amdgcn_mfma_f32_16x16x32_f16((A), (B), (C), 0, 0, 0)

// ---- prep: 13 independent blocks, redundant compute, no cross-block deps ----
__global__ void prep(const float* __restrict__ adj,
                     const float* __restrict__ W_lift,
                     const float* __restrict__ b_lift,
                     const float* __restrict__ W1,
                     const float* __restrict__ b1,
                     const float* __restrict__ W2,
                     const float* __restrict__ b2,
                     const float* __restrict__ W_ro,
                     const float* __restrict__ b_ro,
                     char* __restrict__ ws) {
  const int tid = threadIdx.x;
  const int bx  = blockIdx.x;
  f16* adjb  = (f16*)(ws + WS_ADJB);
  f16* w0b   = (f16*)(ws + WS_W0B);
  f16* mb    = (f16*)(ws + WS_MB);
  float* bia = (float*)(ws + WS_BIAS);
  float* v   = (float*)(ws + WS_V);
  float* u   = (float*)(ws + WS_U);
  float* cp  = (float*)(ws + WS_C);

  if (bx >= 1 && bx <= 8) {
    // K=32 adjacency B-tiles, one gi per block (verified r18).
    const int e = (bx - 1) * 256 + tid;
    const int gi = e >> 8, c = (e >> 6) & 3, lane = e & 63;
    const int lr = lane & 15, q = lane >> 4;
    const float* src = adj + (gi * 16 + lr) * N + c * 32;
    f16* dst = adjb + e * 8;
#pragma unroll
    for (int j = 0; j < 8; ++j) {
      const int col = (j < 4) ? (4 * q + j) : (12 + 4 * q + j);  // lambda
      dst[j] = (f16)src[col];
    }
    return;
  }

  if (bx == 0) {
    // adj column sums -> v; cp = c2r * sum(v) + b_ro.
    __shared__ float vpart[2][N];
    const int c = tid & 127, h = tid >> 7;
    float s = 0.f;
#pragma unroll 8
    for (int i = h * 64; i < h * 64 + 64; ++i) s += adj[i * N + c];
    vpart[h][c] = s;
    __syncthreads();
    if (tid < N) v[tid] = (vpart[0][tid] + vpart[1][tid]) * (1.0f / N);
    if (tid < 64) {
      float sv = (vpart[0][tid] + vpart[1][tid] +
                  vpart[0][64 + tid] + vpart[1][64 + tid]) * (1.0f / N);
      float cc = (tid < 32) ? b2[2 * H + tid] * W_ro[tid] : 0.f;
#pragma unroll
      for (int off = 32; off > 0; off >>= 1) {
        sv += __shfl_down(sv, off, 64);
        cc += __shfl_down(cc, off, 64);
      }
      if (tid == 0) cp[0] = cc * sv + b_ro[0];
    }
    return;
  }

  if (bx == 9) {
    // tmp[0] = W_lift @ W1[0] (rows k<3 live, rest 0) -> w0b pack.
    __shared__ float t0[3][H];
    if (tid < 96) {
      const int k = tid >> 5, fo = tid & 31;
      float val = 0.f;
      for (int c = 0; c < H; ++c) val += W_lift[k * H + c] * W1[c * H + fo];
      t0[k][fo] = val;
    }
    __syncthreads();
    for (int e = tid; e < 512; e += 256) {
      const int t = e >> 8, lane = (e >> 2) & 63, j = e & 3;
      const int lr = lane & 15, q = lane >> 4;
      const int k = q * 4 + j;
      w0b[e] = (f16)((k < 3) ? t0[k][t * 16 + lr] : 0.f);
    }
    return;
  }

  if (bx == 10 || bx == 11) {
    // tmp[l] = W2[l-1] @ W1[l] -> mb[l-1] pack (lambda-permuted K=32 rows).
    const int l = bx - 9;  // 1 or 2
    __shared__ float tl[H][H];
    const float* w2l = W2 + (l - 1) * H * H;
    const float* w1n = W1 + l * H * H;
    for (int idx = tid; idx < H * H; idx += 256) {
      const int k = idx >> 5, fo = idx & 31;
      float val = 0.f;
      for (int c = 0; c < H; ++c) val += w2l[k * H + c] * w1n[c * H + fo];
      tl[k][fo] = val;
    }
    __syncthreads();
    for (int e = tid; e < 1024; e += 256) {
      const int t = e >> 9, lane = (e >> 3) & 63, j = e & 7;
      const int lr = lane & 15, q = lane >> 4;
      const int k = (j < 4) ? (4 * q + j) : (12 + 4 * q + j);  // lambda
      mb[(l - 1) * 1024 + e] = (f16)tl[k][t * 16 + lr];
    }
    return;
  }

  // bx == 12: folded biases (3 x 32 dots) + u (32 dots), one dot per thread.
  if (tid < 96) {
    const int p = tid >> 5, fo = tid & 31;
    if (p == 0) {
      float s = b1[fo];
      for (int c = 0; c < H; ++c) s += b_lift[c] * W1[c * H + fo];
      bia[fo] = s;
    } else if (p == 1) {
      float s = b1[H + fo];
      for (int c = 0; c < H; ++c) s += b2[c] * W1[H * H + c * H + fo];
      bia[H + fo] = s;
    } else {
      float s = b1[2 * H + fo];
      for (int c = 0; c < H; ++c) s += b2[H + c] * W1[2 * H * H + c * H + fo];
      bia[2 * H + fo] = s;
    }
  } else if (tid < 128) {
    const int f = tid & 31;
    float su = 0.f;
    for (int c = 0; c < H; ++c) su += W2[2 * H * H + f * H + c] * W_ro[c];
    u[f] = su;
  }
}

__global__ __launch_bounds__(256, 2)
void gnn_mfma(const float* __restrict__ x,
              const char* __restrict__ ws,
              float* __restrict__ out) {
  const f16* adjb  = (const f16*)(ws + WS_ADJB);
  const f16* w0b   = (const f16*)(ws + WS_W0B);
  const f16* mb    = (const f16*)(ws + WS_MB);
  const float* bia = (const float*)(ws + WS_BIAS);
  const float* v   = (const float*)(ws + WS_V);
  const float* u   = (const float*)(ws + WS_U);
  const float* cp  = (const float*)(ws + WS_C);

  const int tid  = threadIdx.x;
  const int wave = tid >> 6;
  const int lane = tid & 63;
  const int lrow = lane & 15;
  const int quad = lane >> 4;
  const int b0   = blockIdx.x * 8 + wave * 2;
  const int b1   = b0 + 1;

  const f32x4 zero = {0.f, 0.f, 0.f, 0.f};

  // Persistent 2-batch state (32 half8 = 128 VGPR across the ping-pong).
  half8 caA0, caA1, caA2, caA3, cbA0, cbA1, cbA2, cbA3;
  half8 caB0, caB1, caB2, caB3, cbB0, cbB1, cbB2, cbB3;
  half8 pfA0, pfA1, pfA2, pfA3, pfA4, pfA5, pfA6, pfA7;
  half8 pfB0, pfB1, pfB2, pfB3, pfB4, pfB5, pfB6, pfB7;
  // adjb register double-buffer + prefetched m-tiles.
  half8 bp0, bp1, bp2, bp3, bq0, bq1, bq2, bq3;
  half8 mw0, mw1;
  // Deferred-conversion accumulator ping-pong (X/Y), +16 AGPR deliberate.
  f32x4 xA0, xA1, xB0, xB1, yA0, yA1, yB0, yB1;

#define GLOAD(gi, B0, B1, B2, B3)                                            \
  {                                                                          \
    const f16* ab = adjb + ((gi) * 256 + lane) * 8;                          \
    B0 = *(const half8*)(ab + 0 * 512);                                      \
    B1 = *(const half8*)(ab + 1 * 512);                                      \
    B2 = *(const half8*)(ab + 2 * 512);                                      \
    B3 = *(const half8*)(ab + 3 * 512);                                      \
  }
// MFMA region: 16 MFMAs into acc set A* + embedded conversion of the OTHER
// set P* (previous region's accs) inside the same setprio bracket.
#define GREG(B0, B1, B2, B3, A0, A1, A2, A3, P0, P1, P2, P3, PFA, PFB)       \
  {                                                                          \
    __builtin_amdgcn_s_setprio(1);                                           \
    A0 = MF32(caA0, B0, zero); A1 = MF32(cbA0, B0, zero);                    \
    A2 = MF32(caB0, B0, zero); A3 = MF32(cbB0, B0, zero);                    \
    PFA = cat(pkc(P0), pkc(P1));                                             \
    A0 = MF32(caA1, B1, A0); A1 = MF32(cbA1, B1, A1);                        \
    A2 = MF32(caB1, B1, A2); A3 = MF32(cbB1, B1, A3);                        \
    PFB = cat(pkc(P2), pkc(P3));                                             \
    A0 = MF32(caA2, B2, A0); A1 = MF32(cbA2, B2, A1);                        \
    A2 = MF32(caB2, B2, A2); A3 = MF32(cbB2, B2, A3);                        \
    A0 = MF32(caA3, B3, A0); A1 = MF32(cbA3, B3, A1);                        \
    A2 = MF32(caB3, B3, A2); A3 = MF32(cbB3, B3, A3);                        \
    __builtin_amdgcn_s_setprio(0);                                           \
  }
// First region of a G stage: no previous accs to convert.
#define GREG0(B0, B1, B2, B3, A0, A1, A2, A3)                                \
  {                                                                          \
    __builtin_amdgcn_s_setprio(1);                                           \
    A0 = MF32(caA0, B0, zero); A1 = MF32(cbA0, B0, zero);                    \
    A2 = MF32(caB0, B0, zero); A3 = MF32(cbB0, B0, zero);                    \
    A0 = MF32(caA1, B1, A0); A1 = MF32(cbA1, B1, A1);                        \
    A2 = MF32(caB1, B1, A2); A3 = MF32(cbB1, B1, A3);                        \
    A0 = MF32(caA2, B2, A0); A1 = MF32(cbA2, B2, A1);                        \
    A2 = MF32(caB2, B2, A2); A3 = MF32(cbB2, B2, A3);                        \
    A0 = MF32(caA3, B3, A0); A1 = MF32(cbA3, B3, A1);                        \
    A2 = MF32(caB3, B3, A2); A3 = MF32(cbB3, B3, A3);                        \
    __builtin_amdgcn_s_setprio(0);                                           \
  }

  // ---- prologue: hoist scalars + first G-tiles (latency hidden by L0) ----
  const float cpv = cp[0];
  const float u0 = u[lrow], u1 = u[16 + lrow];
  const float bL1a = bia[H + lrow], bL1b = bia[H + 16 + lrow];
  const float bL2a = bia[2 * H + lrow], bL2b = bia[2 * H + 16 + lrow];
  GLOAD(0, bp0, bp1, bp2, bp3)
  GLOAD(1, bq0, bq1, bq2, bq3)

  // ---- L0: T0 = relu(x·W1eff + b0), K=16 MFMA, both batches ----
  {
    const half4 w0 = *(const half4*)(w0b + (0 * 64 + lane) * 4);
    const half4 w1 = *(const half4*)(w0b + (1 * 64 + lane) * 4);
    const float bb0 = bia[lrow], bb1 = bia[16 + lrow];
    const f32x4 bi0 = {bb0, bb0, bb0, bb0};
    const f32x4 bi1 = {bb1, bb1, bb1, bb1};
#define L0PAIR(g, CAA, CBA, CAB, CBB)                                        \
    {                                                                        \
      half4 la0 = {}, la1 = {}, lb0 = {}, lb1 = {};                          \
      if (quad == 0) {                                                       \
        const float* ra0 = x + ((size_t)b0 * N + (g) * 16 + lrow) * 3;       \
        const float* ra1 = x + ((size_t)b0 * N + ((g) + 1) * 16 + lrow) * 3; \
        const float* rb0 = x + ((size_t)b1 * N + (g) * 16 + lrow) * 3;       \
        const float* rb1 = x + ((size_t)b1 * N + ((g) + 1) * 16 + lrow) * 3; \
        la0 = pk4(ra0[0], ra0[1], ra0[2], 0.f);                              \
        la1 = pk4(ra1[0], ra1[1], ra1[2], 0.f);                              \
        lb0 = pk4(rb0[0], rb0[1], rb0[2], 0.f);                              \
        lb1 = pk4(rb1[0], rb1[1], rb1[2], 0.f);                              \
      }                                                                      \
      CAA = cat(relupk(MF(la0, w0, bi0)), relupk(MF(la1, w0, bi0)));         \
      CBA = cat(relupk(MF(la0, w1, bi1)), relupk(MF(la1, w1, bi1)));         \
      CAB = cat(relupk(MF(lb0, w0, bi0)), relupk(MF(lb1, w0, bi0)));         \
      CBB = cat(relupk(MF(lb0, w1, bi1)), relupk(MF(lb1, w1, bi1)));         \
    }
    L0PAIR(0, caA0, cbA0, caB0, cbB0) L0PAIR(2, caA1, cbA1, caB1, cbB1)
    L0PAIR(4, caA2, cbA2, caB2, cbB2) L0PAIR(6, caA3, cbA3, caB3, cbB3)
#undef L0PAIR
  }

  // ---- G0: region g computes gi=g; converts gi=g-1 inside the bracket ----
  GREG0(bp0, bp1, bp2, bp3, xA0, xA1, xB0, xB1)
  GLOAD(2, bp0, bp1, bp2, bp3)
  GREG(bq0, bq1, bq2, bq3, yA0, yA1, yB0, yB1, xA0, xA1, xB0, xB1, pfA0, pfB0)
  GLOAD(3, bq0, bq1, bq2, bq3)
  GREG(bp0, bp1, bp2, bp3, xA0, xA1, xB0, xB1, yA0, yA1, yB0, yB1, pfA1, pfB1)
  GLOAD(4, bp0, bp1, bp2, bp3)
  GREG(bq0, bq1, bq2, bq3, yA0, yA1, yB0, yB1, xA0, xA1, xB0, xB1, pfA2, pfB2)
  GLOAD(5, bq0, bq1, bq2, bq3)
  GREG(bp0, bp1, bp2, bp3, xA0, xA1, xB0, xB1, yA0, yA1, yB0, yB1, pfA3, pfB3)
  GLOAD(6, bp0, bp1, bp2, bp3)
  GREG(bq0, bq1, bq2, bq3, yA0, yA1, yB0, yB1, xA0, xA1, xB0, xB1, pfA4, pfB4)
  GLOAD(7, bq0, bq1, bq2, bq3)
  GREG(bp0, bp1, bp2, bp3, xA0, xA1, xB0, xB1, yA0, yA1, yB0, yB1, pfA5, pfB5)
  { // prefetch L1 m-tiles
    mw0 = *(const half8*)(mb + (0 * 64 + lane) * 8);
    mw1 = *(const half8*)(mb + (1 * 64 + lane) * 8);
  }
  GREG(bq0, bq1, bq2, bq3, yA0, yA1, yB0, yB1, xA0, xA1, xB0, xB1, pfA6, pfB6)
  GLOAD(0, bp0, bp1, bp2, bp3) GLOAD(1, bq0, bq1, bq2, bq3)  // G1 tiles
  // tail conversion flows fence-free into L1's MFMA region
  pfA7 = cat(pkc(yA0), pkc(yA1)); pfB7 = cat(pkc(yB0), pkc(yB1));

  // ---- L1: consumes pf pairs, emits G-friendly cats; both batches ----
  {
    const f32x4 bi0 = {bL1a, bL1a, bL1a, bL1a};
    const f32x4 bi1 = {bL1b, bL1b, bL1b, bL1b};
#define L1PAIR(PF0, PF1, CA, CB)                                             \
    {                                                                        \
      f32x4 c0a = MF32(PF0, mw0, bi0);                                       \
      f32x4 c1a = MF32(PF0, mw1, bi1);                                       \
      f32x4 c0b = MF32(PF1, mw0, bi0);                                       \
      f32x4 c1b = MF32(PF1, mw1, bi1);                                       \
      CA = cat(relupk(c0a), relupk(c0b));                                    \
      CB = cat(relupk(c1a), relupk(c1b));                                    \
    }
    L1PAIR(pfA0, pfA1, caA0, cbA0) L1PAIR(pfB0, pfB1, caB0, cbB0)
    L1PAIR(pfA2, pfA3, caA1, cbA1) L1PAIR(pfB2, pfB3, caB1, cbB1)
    L1PAIR(pfA4, pfA5, caA2, cbA2) L1PAIR(pfB4, pfB5, caB2, cbB2)
    L1PAIR(pfA6, pfA7, caA3, cbA3) L1PAIR(pfB6, pfB7, caB3, cbB3)
#undef L1PAIR
  }

  // ---- G1: same pipeline; region6 prefetches L2 m-tiles ----
  GREG0(bp0, bp1, bp2, bp3, xA0, xA1, xB0, xB1)
  GLOAD(2, bp0, bp1, bp2, bp3)
  GREG(bq0, bq1, bq2, bq3, yA0, yA1, yB0, yB1, xA0, xA1, xB0, xB1, pfA0, pfB0)
  GLOAD(3, bq0, bq1, bq2, bq3)
  GREG(bp0, bp1, bp2, bp3, xA0, xA1, xB0, xB1, yA0, yA1, yB0, yB1, pfA1, pfB1)
  GLOAD(4, bp0, bp1, bp2, bp3)
  GREG(bq0, bq1, bq2, bq3, yA0, yA1, yB0, yB1, xA0, xA1, xB0, xB1, pfA2, pfB2)
  GLOAD(5, bq0, bq1, bq2, bq3)
  GREG(bp0, bp1, bp2, bp3, xA0, xA1, xB0, xB1, yA0, yA1, yB0, yB1, pfA3, pfB3)
  GLOAD(6, bp0, bp1, bp2, bp3)
  GREG(bq0, bq1, bq2, bq3, yA0, yA1, yB0, yB1, xA0, xA1, xB0, xB1, pfA4, pfB4)
  GLOAD(7, bq0, bq1, bq2, bq3)
  GREG(bp0, bp1, bp2, bp3, xA0, xA1, xB0, xB1, yA0, yA1, yB0, yB1, pfA5, pfB5)
  { // prefetch L2 m-tiles
    mw0 = *(const half8*)(mb + 1024 + (0 * 64 + lane) * 8);
    mw1 = *(const half8*)(mb + 1024 + (1 * 64 + lane) * 8);
  }
  GREG(bq0, bq1, bq2, bq3, yA0, yA1, yB0, yB1, xA0, xA1, xB0, xB1, pfA6, pfB6)
  pfA7 = cat(pkc(yA0), pkc(yA1)); pfB7 = cat(pkc(yB0), pkc(yB1));

#undef GREG
#undef GREG0
#undef GLOAD

  // ---- L2 + folded readout, both batches ----
  {
    const f32x4 bi0 = {bL2a, bL2a, bL2a, bL2a};
    const f32x4 bi1 = {bL2b, bL2b, bL2b, bL2b};
    float pA = 0.f, pB = 0.f;
#define L2G(g, PF, ACC)                                                      \
    {                                                                        \
      f32x4 c0 = MF32(PF, mw0, bi0);                                         \
      f32x4 c1 = MF32(PF, mw1, bi1);                                         \
      const float4 vv = *(const float4*)(v + (g) * 16 + quad * 4);           \
      ACC += (fmaxf(c0[0], 0.f) * vv.x + fmaxf(c0[1], 0.f) * vv.y +          \
              fmaxf(c0[2], 0.f) * vv.z + fmaxf(c0[3], 0.f) * vv.w) * u0 +    \
             (fmaxf(c1[0], 0.f) * vv.x + fmaxf(c1[1], 0.f) * vv.y +          \
              fmaxf(c1[2], 0.f) * vv.z + fmaxf(c1[3], 0.f) * vv.w) * u1;     \
    }
    L2G(0, pfA0, pA) L2G(0, pfB0, pB) L2G(1, pfA1, pA) L2G(1, pfB1, pB)
    L2G(2, pfA2, pA) L2G(2, pfB2, pB) L2G(3, pfA3, pA) L2G(3, pfB3, pB)
    L2G(4, pfA4, pA) L2G(4, pfB4, pB) L2G(5, pfA5, pA) L2G(5, pfB5, pB)
    L2G(6, pfA6, pA) L2G(6, pfB6, pB) L2G(7, pfA7, pA) L2G(7, pfB7, pB)
#undef L2G
#pragma unroll
    for (int off = 32; off > 0; off >>= 1) {
      pA += __shfl_down(pA, off, 64);
      pB += __shfl_down(pB, off, 64);
    }
    if (lane == 0) {
      out[b0] = pA + cpv;
      out[b1] = pB + cpv;
    }
  }
}

extern "C" void kernel_launch(void* const* d_in, const int* in_sizes, int n_in,
                              void* d_out, int out_size, void* d_ws, size_t ws_size,
                              hipStream_t stream) {
  const float* x      = (const float*)d_in[0];
  const float* adj    = (const float*)d_in[1];
  const float* W_lift = (const float*)d_in[2];
  const float* b_lift = (const float*)d_in[3];
  const float* W1     = (const float*)d_in[4];
  const float* b1     = (const float*)d_in[5];
  const float* W2     = (const float*)d_in[6];
  const float* b2     = (const float*)d_in[7];
  const float* W_ro   = (const float*)d_in[8];
  const float* b_ro   = (const float*)d_in[9];
  char* ws = (char*)d_ws;
  float* o = (float*)d_out;

  const int B = in_sizes[0] / (N * 3);   // 16384
  hipLaunchKernelGGL(prep, dim3(13), dim3(256), 0, stream,
                     adj, W_lift, b_lift, W1, b1, W2, b2, W_ro, b_ro, ws);
  hipLaunchKernelGGL(gnn_mfma, dim3(B / 8), dim3(256), 0, stream,
                     x, (const char*)ws, o);
}